// Round 1
// baseline (1150.561 us; speedup 1.0000x reference)
//
#include <hip/hip_runtime.h>
#include <math.h>

#define HW (512*512)
#define WID 512
#define HEI 512
#define MM 128

// Monotone map: larger float  =>  larger uint key (handles negatives, NaN maps above +inf
// which matches jnp.argmax NaN-propagation; irrelevant for normal inputs).
__device__ __forceinline__ unsigned long long pack_fi(float v, unsigned int idx) {
    unsigned int b = __float_as_uint(v);
    unsigned int key = (b & 0x80000000u) ? ~b : (b | 0x80000000u);
    // smaller index wins on equal value (first-occurrence argmax)
    return ((unsigned long long)key << 32) | (unsigned long long)(0xFFFFFFFFu - idx);
}

// grid: (256, 10), block: 256. Each block reduces 1024 contiguous elements (256 float4)
// of one heatmap and writes one packed partial -> no atomics, no ws pre-init needed.
__global__ __launch_bounds__(256) void argmax_part(const float* __restrict__ heat,
                                                   unsigned long long* __restrict__ part) {
    const int m = blockIdx.y;
    const int b = blockIdx.x;
    const int t = threadIdx.x;
    const float4* hp = (const float4*)(heat + (size_t)m * HW);
    const int i4 = b * 256 + t;
    float4 v = hp[i4];
    unsigned int base = (unsigned int)(i4 * 4);
    unsigned long long best = pack_fi(v.x, base);
    unsigned long long c;
    c = pack_fi(v.y, base + 1); if (c > best) best = c;
    c = pack_fi(v.z, base + 2); if (c > best) best = c;
    c = pack_fi(v.w, base + 3); if (c > best) best = c;

    // wave64 shuffle reduce
    #pragma unroll
    for (int off = 32; off > 0; off >>= 1) {
        unsigned long long o = __shfl_down(best, (unsigned)off, 64);
        if (o > best) best = o;
    }
    __shared__ unsigned long long sm[4];
    const int wave = t >> 6, lane = t & 63;
    if (lane == 0) sm[wave] = best;
    __syncthreads();
    if (t == 0) {
        best = sm[0];
        #pragma unroll
        for (int wv = 1; wv < 4; ++wv) if (sm[wv] > best) best = sm[wv];
        part[m * 256 + b] = best;
    }
}

// grid: 10 blocks (one per point), block: 256.
__global__ __launch_bounds__(256) void compute_out(const float* __restrict__ feats,
                                                   const unsigned long long* __restrict__ part,
                                                   float* __restrict__ out) {
    const int m = blockIdx.x;
    const int t = threadIdx.x;

    // ---- final argmax reduce over this map's 256 partials ----
    __shared__ unsigned long long sred[256];
    sred[t] = part[m * 256 + t];
    __syncthreads();
    #pragma unroll
    for (int s = 128; s > 0; s >>= 1) {
        if (t < s) { if (sred[t + s] > sred[t]) sred[t] = sred[t + s]; }
        __syncthreads();
    }
    const unsigned int idx = 0xFFFFFFFFu - (unsigned int)(sred[0] & 0xFFFFFFFFull);
    const int py = (int)(idx >> 9);    // idx / 512
    const int px = (int)(idx & 511u);  // idx % 512

    const float* __restrict__ saliency    = feats;                     // ch 0
    const float* __restrict__ shape_feats = feats + (size_t)1 * HW;    // ch 1..1024
    const float* __restrict__ sizec       = feats + (size_t)1025 * HW; // ch 1025,1026

    // ---- stage the 32x32 shape vector (1024 strided gathers) ----
    __shared__ float svec[1024];
    const int pofs = py * WID + px;
    for (int cch = t; cch < 1024; cch += 256)
        svec[cch] = shape_feats[(size_t)cch * HW + pofs];

    __shared__ int sh_h, sh_w;
    if (t == 0) {
        int hh = (int)fabsf(sizec[pofs]);          // trunc toward zero, like astype(int32)
        int ww = (int)fabsf(sizec[HW + pofs]);
        sh_h = min(max(hh, 1), MM);
        sh_w = min(max(ww, 1), MM);
    }
    __syncthreads();
    const int h = sh_h, w = sh_w;

    // ---- sampling coordinate tables ----
    __shared__ float s_sy[MM], s_sx[MM];
    if (t < MM) {
        float r = (float)t;
        float sy = ((r + 0.5f) * 32.0f) / (float)h - 0.5f;
        s_sy[t] = fminf(fmaxf(sy, 0.0f), 31.0f);
        float sx = ((r + 0.5f) * 32.0f) / (float)w - 0.5f;
        s_sx[t] = fminf(fmaxf(sx, 0.0f), 31.0f);
    }
    __syncthreads();

    float* __restrict__ outp = out + (size_t)m * (MM * MM);
    const int h2 = h >> 1, w2 = w >> 1;

    #pragma unroll
    for (int k = 0; k < (MM * MM) / 256; ++k) {
        const int pix = t + k * 256;
        const int i = pix >> 7;
        const int j = pix & 127;
        float res = 0.0f;
        const int gr = py - h2 + i;
        const int gc = px - w2 + j;
        const bool valid = (i < h) & (j < w) & (gr >= 0) & (gr < HEI) & (gc >= 0) & (gc < WID);
        if (valid) {
            const float sy = s_sy[i], sx = s_sx[j];
            const int y0 = (int)floorf(sy);
            const int y1 = min(y0 + 1, 31);
            const float wy = sy - (float)y0;
            const int x0 = (int)floorf(sx);
            const int x1 = min(x0 + 1, 31);
            const float wx = sx - (float)x0;
            // exact reference order: interpolate y first, then x
            const float ra = svec[y0 * 32 + x0] * (1.0f - wy) + svec[y1 * 32 + x0] * wy;
            const float rb = svec[y0 * 32 + x1] * (1.0f - wy) + svec[y1 * 32 + x1] * wy;
            const float local = ra * (1.0f - wx) + rb * wx;
            const float sig = 1.0f / (1.0f + expf(-local));
            res = sig * saliency[gr * WID + gc];   // valid => in-bounds, no clip needed
        }
        outp[pix] = res;
    }
}

extern "C" void kernel_launch(void* const* d_in, const int* in_sizes, int n_in,
                              void* d_out, int out_size, void* d_ws, size_t ws_size,
                              hipStream_t stream) {
    const float* feats = (const float*)d_in[0];
    const float* heat = feats + (size_t)1027 * HW;
    unsigned long long* part = (unsigned long long*)d_ws; // 10*256*8 = 20480 B

    dim3 g1(256, 10);
    argmax_part<<<g1, dim3(256), 0, stream>>>(heat, part);
    compute_out<<<dim3(10), dim3(256), 0, stream>>>(feats, part, (float*)d_out);
}